// Round 13
// baseline (5829.752 us; speedup 1.0000x reference)
//
#include <hip/hip_runtime.h>
#include <hip/hip_bf16.h>

#define DD 512
#define LL 512
#define BB 64
#define NT 1536
#define MROWS (LL*BB)

typedef short short8 __attribute__((ext_vector_type(8)));
typedef float floatx4 __attribute__((ext_vector_type(4)));
union U4S8 { uint4 u4; short8 s8; };
typedef unsigned long long ull;

static __device__ __forceinline__ unsigned short f2bf(float f) {
  unsigned int u = __float_as_uint(f);
  unsigned int r = (u + 0x7fffu + ((u >> 16) & 1u)) >> 16;
  return (unsigned short)r;
}
static __device__ __forceinline__ float bf2f(unsigned short s) {
  return __uint_as_float(((unsigned int)s) << 16);
}

// Pack Wc[s][512 k][1024 col] f32 -> MFMA B-fragments, bf16 pairs (round-5 proven layout).
__global__ void pack_wc_k(const float* __restrict__ Wc, unsigned int* __restrict__ Wp) {
  int U = blockIdx.x * 256 + threadIdx.x;      // [0, 4*8*32768)
  int sdg = U >> 15;
  int s = sdg >> 3, dg = sdg & 7;
  int r = U & 32767;
  int u = r & 3;
  int lane = (r >> 2) & 63;
  int fidx = r >> 8;            // 0..127 = w*16 + ct*2 + kt
  int kt = fidx & 1;
  int ct = (fidx >> 1) & 7;
  int w = fidx >> 4;
  int k = w * 64 + kt * 32 + 8 * (lane >> 4) + 2 * u;
  int cl = ct * 16 + (lane & 15);
  int gcol = (cl >> 6) * 512 + dg * 64 + (cl & 63);
  size_t base = (size_t)s * DD * 1024;
  float lo = Wc[base + (size_t)k * 1024 + gcol];
  float hi = Wc[base + (size_t)(k + 1) * 1024 + gcol];
  Wp[U] = (unsigned int)f2bf(lo) | ((unsigned int)f2bf(hi) << 16);
}

// Transpose Wx[s][512 k][1536 n] f32 -> Wxp[s][1536 n][512 k] bf16 (tiled).
__global__ __launch_bounds__(256)
void pack_wx_k(const float* __restrict__ W, unsigned short* __restrict__ Wxp) {
  __shared__ float t[64][65];
  int k0 = blockIdx.x * 64, n0 = blockIdx.y * 64, s = blockIdx.z;
  int tx = threadIdx.x & 63, ty = threadIdx.x >> 6;
  const float* Wb = W + (size_t)s * DD * NT;
#pragma unroll
  for (int i = 0; i < 16; ++i) {
    int k = ty * 16 + i;
    t[k][tx] = Wb[(size_t)(k0 + k) * NT + n0 + tx];
  }
  __syncthreads();
  unsigned short* Ob = Wxp + (size_t)s * NT * DD;
#pragma unroll
  for (int i = 0; i < 16; ++i) {
    int n = ty * 16 + i;
    Ob[(size_t)(n0 + n) * DD + k0 + tx] = f2bf(t[tx][n]);
  }
}

__global__ void gather_k(const int* __restrict__ xs, const float* __restrict__ emb,
                         float* __restrict__ x) {
  int i = blockIdx.x * 256 + threadIdx.x;
  int row = i >> 7;
  int col = i & 127;
  const float4* src = (const float4*)(emb + (size_t)xs[row] * DD);
  ((float4*)(x + (size_t)row * DD))[col] = src[col];
}

// ---------------- fallback fp32 GEMM (proven) ----------------
__global__ __launch_bounds__(256)
void gemm_k(const float* __restrict__ A, const float* __restrict__ W,
            const float* __restrict__ bias, unsigned short* __restrict__ C) {
  __shared__ float As[16][128];
  __shared__ float Bs[16][128];
  const int tid = threadIdx.x;
  const int tx = tid & 15;
  const int ty = tid >> 4;
  const int m0 = blockIdx.y * 128;
  const int n0 = blockIdx.x * 128;
  const int lm = tid >> 1;
  const int lk = (tid & 1) * 8;
  const int wk = tid >> 4;
  const int wn = (tid & 15) * 8;
  float acc[8][8];
#pragma unroll
  for (int i = 0; i < 8; ++i)
#pragma unroll
    for (int j = 0; j < 8; ++j) acc[i][j] = 0.f;
  for (int k0 = 0; k0 < DD; k0 += 16) {
    float4 a0 = *(const float4*)(A + (size_t)(m0 + lm) * DD + k0 + lk);
    float4 a1 = *(const float4*)(A + (size_t)(m0 + lm) * DD + k0 + lk + 4);
    float4 w0 = *(const float4*)(W + (size_t)(k0 + wk) * NT + n0 + wn);
    float4 w1 = *(const float4*)(W + (size_t)(k0 + wk) * NT + n0 + wn + 4);
    __syncthreads();
    As[lk + 0][lm] = a0.x; As[lk + 1][lm] = a0.y; As[lk + 2][lm] = a0.z; As[lk + 3][lm] = a0.w;
    As[lk + 4][lm] = a1.x; As[lk + 5][lm] = a1.y; As[lk + 6][lm] = a1.z; As[lk + 7][lm] = a1.w;
    *(float4*)&Bs[wk][wn] = w0;
    *(float4*)&Bs[wk][wn + 4] = w1;
    __syncthreads();
#pragma unroll
    for (int kk = 0; kk < 16; ++kk) {
      float a[8], w[8];
      *(float4*)&a[0] = *(const float4*)&As[kk][ty * 8];
      *(float4*)&a[4] = *(const float4*)&As[kk][ty * 8 + 4];
      *(float4*)&w[0] = *(const float4*)&Bs[kk][tx * 8];
      *(float4*)&w[4] = *(const float4*)&Bs[kk][tx * 8 + 4];
#pragma unroll
      for (int i = 0; i < 8; ++i)
#pragma unroll
        for (int j = 0; j < 8; ++j)
          acc[i][j] = fmaf(a[i], w[j], acc[i][j]);
    }
  }
#pragma unroll
  for (int i = 0; i < 8; ++i) {
    size_t rb = (size_t)(m0 + ty * 8 + i) * NT + n0 + tx * 8;
#pragma unroll
    for (int jv = 0; jv < 2; ++jv) {
      ushort4 v;
      v.x = f2bf(acc[i][jv*4+0] + bias[n0 + tx*8 + jv*4 + 0]);
      v.y = f2bf(acc[i][jv*4+1] + bias[n0 + tx*8 + jv*4 + 1]);
      v.z = f2bf(acc[i][jv*4+2] + bias[n0 + tx*8 + jv*4 + 2]);
      v.w = f2bf(acc[i][jv*4+3] + bias[n0 + tx*8 + jv*4 + 3]);
      *(ushort4*)(C + rb + jv*4) = v;
    }
  }
}

// ---------------- bf16 MFMA GEMM, software-pipelined staging ----------------
// Only change vs round 7: iteration k+1's global loads are issued right after
// the LDS writes of iteration k, so HBM latency hides under the 16-MFMA phase.
__global__ __launch_bounds__(256)
void gemm_m_k(const float* __restrict__ A, const unsigned short* __restrict__ Wt,
              const float* __restrict__ bias, unsigned short* __restrict__ C) {
  __shared__ unsigned short Al[128 * 40];
  __shared__ unsigned short Bl[128 * 40];
  const int tid = threadIdx.x;
  const int m0 = blockIdx.y * 128, n0 = blockIdx.x * 128;
  const int wave = tid >> 6, lane = tid & 63;
  const int wm = wave >> 1, wn = wave & 1;
  const int l15 = lane & 15, lh = lane >> 4;
  floatx4 acc[4][4];
#pragma unroll
  for (int i = 0; i < 4; ++i)
#pragma unroll
    for (int j = 0; j < 4; ++j) acc[i][j] = (floatx4){0.f, 0.f, 0.f, 0.f};

  const int ar = tid >> 3, ac = (tid & 7) * 4;
  const int br = tid >> 2, bc = (tid & 3) * 8;

  float4 av[4];
  uint4 bv0, bv1;
  // prologue: load k0 = 0
#pragma unroll
  for (int p = 0; p < 4; ++p)
    av[p] = *(const float4*)(A + (size_t)(m0 + ar + p * 32) * DD + ac);
  bv0 = *(const uint4*)(Wt + (size_t)(n0 + br) * DD + bc);
  bv1 = *(const uint4*)(Wt + (size_t)(n0 + br + 64) * DD + bc);

#pragma unroll 1
  for (int k0 = 0; k0 < DD; k0 += 32) {
    __syncthreads();               // LDS free (previous MFMA phase done)
#pragma unroll
    for (int p = 0; p < 4; ++p) {
      ushort4 w4;
      w4.x = f2bf(av[p].x); w4.y = f2bf(av[p].y);
      w4.z = f2bf(av[p].z); w4.w = f2bf(av[p].w);
      *(ushort4*)&Al[(ar + p * 32) * 40 + ac] = w4;
    }
    *(uint4*)&Bl[br * 40 + bc] = bv0;
    *(uint4*)&Bl[(br + 64) * 40 + bc] = bv1;
    __syncthreads();
    // issue next tile's loads early — latency hides under the MFMAs below
    if (k0 + 32 < DD) {
#pragma unroll
      for (int p = 0; p < 4; ++p)
        av[p] = *(const float4*)(A + (size_t)(m0 + ar + p * 32) * DD + k0 + 32 + ac);
      bv0 = *(const uint4*)(Wt + (size_t)(n0 + br) * DD + k0 + 32 + bc);
      bv1 = *(const uint4*)(Wt + (size_t)(n0 + br + 64) * DD + k0 + 32 + bc);
    }
    U4S8 af[4], bfr[4];
#pragma unroll
    for (int mf = 0; mf < 4; ++mf)
      af[mf].u4 = *(const uint4*)&Al[(wm * 64 + mf * 16 + l15) * 40 + lh * 8];
#pragma unroll
    for (int nf = 0; nf < 4; ++nf)
      bfr[nf].u4 = *(const uint4*)&Bl[(wn * 64 + nf * 16 + l15) * 40 + lh * 8];
#pragma unroll
    for (int mf = 0; mf < 4; ++mf)
#pragma unroll
      for (int nf = 0; nf < 4; ++nf)
        acc[mf][nf] = __builtin_amdgcn_mfma_f32_16x16x32_bf16(
            af[mf].s8, bfr[nf].s8, acc[mf][nf], 0, 0, 0);
  }
#pragma unroll
  for (int nf = 0; nf < 4; ++nf) {
    int n = n0 + wn * 64 + nf * 16 + l15;
    float bn = bias[n];
#pragma unroll
    for (int mf = 0; mf < 4; ++mf) {
      int row = m0 + wm * 64 + mf * 16 + lh * 4;
      size_t base = (size_t)row * NT + n;
#pragma unroll
      for (int e = 0; e < 4; ++e)
        C[base + (size_t)e * NT] = f2bf(acc[mf][nf][e] + bn);
    }
  }
}

// ---------------- scan: round-12 proven kernel (byte-identical) ----------------
__global__ __launch_bounds__(512, 1)
void scan_k(const unsigned short* __restrict__ gx,
            const uint4* __restrict__ Wsc,
            const float* __restrict__ xin,
            float* __restrict__ hout,
            float* __restrict__ cbuf,           // [64][512] f32
            unsigned short* __restrict__ xbu,   // [2][64][512] bf16
            unsigned int* __restrict__ flags,   // [8 bg][8 dg] monotonic
            int reverse, unsigned int step_base) {
  __shared__ float pd[8192];                    // 32 KiB partials
  const int tid = threadIdx.x;
  const int bg = blockIdx.x & 7;
  const int dg = blockIdx.x >> 3;
  const int lane = tid & 63;
  const int w = tid >> 6;
  const int batch = bg * 8 + w;
  const int dim = dg * 64 + lane;

  uint4 Wf[16];
  {
    const uint4* ws = Wsc + (size_t)dg * 8192;
#pragma unroll
    for (int f = 0; f < 16; ++f)
      Wf[f] = ws[(size_t)(w * 16 + f) * 64 + lane];
  }
  float c_reg = cbuf[batch * DD + dim];
  int t0 = reverse ? (LL - 1) : 0;
  size_t r0 = (size_t)t0 * BB + batch;
  float g_i = bf2f(gx[r0 * NT + dim]);
  float g_f = bf2f(gx[r0 * NT + 512 + dim]);
  float g_c = bf2f(gx[r0 * NT + 1024 + dim]);
  float x_v = xin[r0 * DD + dim];
  const int arow = lane & 7, lh = lane >> 4;

#pragma unroll 1
  for (int s = 0; s < LL; ++s) {
    unsigned int need = step_base + (unsigned int)s;
    // ---- per-wave gate: partner block (bg, w) has published step s-1 ----
    {
      const unsigned int* f = flags + bg * 8 + w;
      while (__hip_atomic_load(f, __ATOMIC_RELAXED, __HIP_MEMORY_SCOPE_AGENT) < need)
        __builtin_amdgcn_s_sleep(1);
    }
    // ---- A-frags direct from exchange buffer, parity (s+1)&1 ----
    const ull* src = (const ull*)xbu + (size_t)(((s + 1) & 1)) * 8192;
    int ai = (bg * 8 + arow) * 128 + w * 16 + 2 * lh;
    ull v0 = __hip_atomic_load(&src[ai],     __ATOMIC_RELAXED, __HIP_MEMORY_SCOPE_AGENT);
    ull v1 = __hip_atomic_load(&src[ai + 1], __ATOMIC_RELAXED, __HIP_MEMORY_SCOPE_AGENT);
    ull v2 = __hip_atomic_load(&src[ai + 8], __ATOMIC_RELAXED, __HIP_MEMORY_SCOPE_AGENT);
    ull v3 = __hip_atomic_load(&src[ai + 9], __ATOMIC_RELAXED, __HIP_MEMORY_SCOPE_AGENT);
    // ---- MFMA partials over this wave's K-slice ----
    U4S8 A0, A1;
    A0.u4 = make_uint4((unsigned int)v0, (unsigned int)(v0 >> 32),
                       (unsigned int)v1, (unsigned int)(v1 >> 32));
    A1.u4 = make_uint4((unsigned int)v2, (unsigned int)(v2 >> 32),
                       (unsigned int)v3, (unsigned int)(v3 >> 32));
#pragma unroll
    for (int ct = 0; ct < 8; ++ct) {
      U4S8 B0, B1; B0.u4 = Wf[ct * 2]; B1.u4 = Wf[ct * 2 + 1];
      floatx4 acc = __builtin_amdgcn_mfma_f32_16x16x32_bf16(
          A0.s8, B0.s8, (floatx4){0.f, 0.f, 0.f, 0.f}, 0, 0, 0);
      acc = __builtin_amdgcn_mfma_f32_16x16x32_bf16(A1.s8, B1.s8, acc, 0, 0, 0);
      if (lane < 32) {
        int colb = ct * 16 + (lane & 15);
        int rb = (lane >> 4) * 4;
#pragma unroll
        for (int e = 0; e < 4; ++e)
          pd[(w * 8 + rb + e) * 128 + colb] = acc[e];
      }
    }
    __syncthreads();
    // ---- reduce + gates (wave w owns batch bg*8+w, dim = dg*64+lane) ----
    float gsi = 0.f, gsf = 0.f;
#pragma unroll
    for (int ww = 0; ww < 8; ++ww) {
      gsi += pd[(ww * 8 + w) * 128 + lane];
      gsf += pd[(ww * 8 + w) * 128 + 64 + lane];
    }
    float iv = 1.f / (1.f + __expf(-(g_i + gsi)));
    float fv = 1.f / (1.f + __expf(-(g_f + gsf)));
    float cn = fmaf(fv, c_reg, iv * g_c);
    // ---- publish ONLY (2B relaxed agent store; 128B contiguous per wave) ----
    __hip_atomic_store(xbu + (size_t)((s & 1)) * 32768 + batch * DD + dim,
                       f2bf(cn), __ATOMIC_RELAXED, __HIP_MEMORY_SCOPE_AGENT);
    __syncthreads();   // vmcnt(0) drain: publishes device-visible (nothing else pending)
    if (tid == 0)
      __hip_atomic_store(&flags[bg * 8 + dg], need + 1u,
                         __ATOMIC_RELAXED, __HIP_MEMORY_SCOPE_AGENT);
    // ---- off-critical tail AFTER the flag: hout + next-step prefetch ----
    int t = reverse ? (LL - 1 - s) : s;
    size_t rowg = (size_t)t * BB + batch;
    hout[rowg * DD + dim] = tanhf(cn) + x_v;
    c_reg = cn;
    int sn = (s + 1 < LL) ? s + 1 : s;
    int tn = reverse ? (LL - 1 - sn) : sn;
    size_t rn = (size_t)tn * BB + batch;
    g_i = bf2f(gx[rn * NT + dim]);
    g_f = bf2f(gx[rn * NT + 512 + dim]);
    g_c = bf2f(gx[rn * NT + 1024 + dim]);
    x_v = xin[rn * DD + dim];
  }
  cbuf[batch * DD + dim] = c_reg;
}

extern "C" void kernel_launch(void* const* d_in, const int* in_sizes, int n_in,
                              void* d_out, int out_size, void* d_ws, size_t ws_size,
                              hipStream_t stream) {
  const int* xs = (const int*)d_in[0];
  const float* emb = (const float*)d_in[1];
  const float* Wx = (const float*)d_in[2];
  const float* Wc = (const float*)d_in[3];
  const float* bias = (const float*)d_in[4];
  float* out = (float*)d_out;
  char* ws = (char*)d_ws;

  unsigned short* gx = (unsigned short*)ws;                          // 96 MiB
  float* xB = (float*)(ws + (size_t)100663296);                      // 64 MiB
  unsigned int* Wp = (unsigned int*)(ws + (size_t)167772160);        // 4 MiB
  float* cbuf = (float*)(ws + (size_t)171966464);                    // 128 KiB
  unsigned short* xbu = (unsigned short*)(ws + (size_t)172097536);   // 128 KiB
  unsigned int* flags = (unsigned int*)(ws + (size_t)172228608);     // 256 B
  unsigned short* Wxp = (unsigned short*)(ws + (size_t)172229632);   // 6 MiB
  const size_t NEED = 178521088ull;
  const bool use_mfma_gemm = (ws_size >= NEED);

  hipMemsetAsync(cbuf, 0, 131072, stream);
  hipMemsetAsync(xbu, 0, 131072, stream);    // seed parity-1 with bf16(c0)=0
  hipMemsetAsync(flags, 0, 256, stream);
  pack_wc_k<<<4096, 256, 0, stream>>>(Wc, Wp);
  if (use_mfma_gemm)
    pack_wx_k<<<dim3(8, 24, 4), 256, 0, stream>>>(Wx, Wxp);
  gather_k<<<MROWS * 128 / 256, 256, 0, stream>>>(xs, emb, out);

  for (int s = 0; s < 4; ++s) {
    const float* xin = (s % 2 == 0) ? out : xB;
    float* xout = (s % 2 == 0) ? xB : out;
    if (use_mfma_gemm)
      gemm_m_k<<<dim3(NT / 128, MROWS / 128), 256, 0, stream>>>(
          xin, Wxp + (size_t)s * NT * DD, bias + (size_t)s * NT, gx);
    else
      gemm_k<<<dim3(NT / 128, MROWS / 128), 256, 0, stream>>>(
          xin, Wx + (size_t)s * DD * NT, bias + (size_t)s * NT, gx);
    scan_k<<<64, 512, 0, stream>>>(
        gx, (const uint4*)(Wp + (size_t)s * 262144), xin, xout, cbuf, xbu, flags,
        s & 1, (unsigned int)(s * 512));
  }
}

// Round 15
// 5827.843 us; speedup vs baseline: 1.0003x; 1.0003x over previous
//
#include <hip/hip_runtime.h>
#include <hip/hip_bf16.h>

#define DD 512
#define LL 512
#define BB 64
#define NT 1536
#define MROWS (LL*BB)

typedef short short8 __attribute__((ext_vector_type(8)));
typedef float floatx4 __attribute__((ext_vector_type(4)));
union U4S8 { uint4 u4; short8 s8; };
typedef unsigned long long ull;

static __device__ __forceinline__ unsigned short f2bf(float f) {
  unsigned int u = __float_as_uint(f);
  unsigned int r = (u + 0x7fffu + ((u >> 16) & 1u)) >> 16;
  return (unsigned short)r;
}
static __device__ __forceinline__ float bf2f(unsigned short s) {
  return __uint_as_float(((unsigned int)s) << 16);
}

// Pack Wc[s][512 k][1024 col] f32 -> MFMA B-fragments, bf16 pairs (round-5 proven layout).
__global__ void pack_wc_k(const float* __restrict__ Wc, unsigned int* __restrict__ Wp) {
  int U = blockIdx.x * 256 + threadIdx.x;      // [0, 4*8*32768)
  int sdg = U >> 15;
  int s = sdg >> 3, dg = sdg & 7;
  int r = U & 32767;
  int u = r & 3;
  int lane = (r >> 2) & 63;
  int fidx = r >> 8;            // 0..127 = w*16 + ct*2 + kt
  int kt = fidx & 1;
  int ct = (fidx >> 1) & 7;
  int w = fidx >> 4;
  int k = w * 64 + kt * 32 + 8 * (lane >> 4) + 2 * u;
  int cl = ct * 16 + (lane & 15);
  int gcol = (cl >> 6) * 512 + dg * 64 + (cl & 63);
  size_t base = (size_t)s * DD * 1024;
  float lo = Wc[base + (size_t)k * 1024 + gcol];
  float hi = Wc[base + (size_t)(k + 1) * 1024 + gcol];
  Wp[U] = (unsigned int)f2bf(lo) | ((unsigned int)f2bf(hi) << 16);
}

// Transpose Wx[s][512 k][1536 n] f32 -> Wxp[s][1536 n][512 k] bf16 (tiled).
__global__ __launch_bounds__(256)
void pack_wx_k(const float* __restrict__ W, unsigned short* __restrict__ Wxp) {
  __shared__ float t[64][65];
  int k0 = blockIdx.x * 64, n0 = blockIdx.y * 64, s = blockIdx.z;
  int tx = threadIdx.x & 63, ty = threadIdx.x >> 6;
  const float* Wb = W + (size_t)s * DD * NT;
#pragma unroll
  for (int i = 0; i < 16; ++i) {
    int k = ty * 16 + i;
    t[k][tx] = Wb[(size_t)(k0 + k) * NT + n0 + tx];
  }
  __syncthreads();
  unsigned short* Ob = Wxp + (size_t)s * NT * DD;
#pragma unroll
  for (int i = 0; i < 16; ++i) {
    int n = ty * 16 + i;
    Ob[(size_t)(n0 + n) * DD + k0 + tx] = f2bf(t[tx][n]);
  }
}

__global__ void gather_k(const int* __restrict__ xs, const float* __restrict__ emb,
                         float* __restrict__ x) {
  int i = blockIdx.x * 256 + threadIdx.x;
  int row = i >> 7;
  int col = i & 127;
  const float4* src = (const float4*)(emb + (size_t)xs[row] * DD);
  ((float4*)(x + (size_t)row * DD))[col] = src[col];
}

// ---------------- fallback fp32 GEMM (proven) ----------------
__global__ __launch_bounds__(256)
void gemm_k(const float* __restrict__ A, const float* __restrict__ W,
            const float* __restrict__ bias, unsigned short* __restrict__ C) {
  __shared__ float As[16][128];
  __shared__ float Bs[16][128];
  const int tid = threadIdx.x;
  const int tx = tid & 15;
  const int ty = tid >> 4;
  const int m0 = blockIdx.y * 128;
  const int n0 = blockIdx.x * 128;
  const int lm = tid >> 1;
  const int lk = (tid & 1) * 8;
  const int wk = tid >> 4;
  const int wn = (tid & 15) * 8;
  float acc[8][8];
#pragma unroll
  for (int i = 0; i < 8; ++i)
#pragma unroll
    for (int j = 0; j < 8; ++j) acc[i][j] = 0.f;
  for (int k0 = 0; k0 < DD; k0 += 16) {
    float4 a0 = *(const float4*)(A + (size_t)(m0 + lm) * DD + k0 + lk);
    float4 a1 = *(const float4*)(A + (size_t)(m0 + lm) * DD + k0 + lk + 4);
    float4 w0 = *(const float4*)(W + (size_t)(k0 + wk) * NT + n0 + wn);
    float4 w1 = *(const float4*)(W + (size_t)(k0 + wk) * NT + n0 + wn + 4);
    __syncthreads();
    As[lk + 0][lm] = a0.x; As[lk + 1][lm] = a0.y; As[lk + 2][lm] = a0.z; As[lk + 3][lm] = a0.w;
    As[lk + 4][lm] = a1.x; As[lk + 5][lm] = a1.y; As[lk + 6][lm] = a1.z; As[lk + 7][lm] = a1.w;
    *(float4*)&Bs[wk][wn] = w0;
    *(float4*)&Bs[wk][wn + 4] = w1;
    __syncthreads();
#pragma unroll
    for (int kk = 0; kk < 16; ++kk) {
      float a[8], w[8];
      *(float4*)&a[0] = *(const float4*)&As[kk][ty * 8];
      *(float4*)&a[4] = *(const float4*)&As[kk][ty * 8 + 4];
      *(float4*)&w[0] = *(const float4*)&Bs[kk][tx * 8];
      *(float4*)&w[4] = *(const float4*)&Bs[kk][tx * 8 + 4];
#pragma unroll
      for (int i = 0; i < 8; ++i)
#pragma unroll
        for (int j = 0; j < 8; ++j)
          acc[i][j] = fmaf(a[i], w[j], acc[i][j]);
    }
  }
#pragma unroll
  for (int i = 0; i < 8; ++i) {
    size_t rb = (size_t)(m0 + ty * 8 + i) * NT + n0 + tx * 8;
#pragma unroll
    for (int jv = 0; jv < 2; ++jv) {
      ushort4 v;
      v.x = f2bf(acc[i][jv*4+0] + bias[n0 + tx*8 + jv*4 + 0]);
      v.y = f2bf(acc[i][jv*4+1] + bias[n0 + tx*8 + jv*4 + 1]);
      v.z = f2bf(acc[i][jv*4+2] + bias[n0 + tx*8 + jv*4 + 2]);
      v.w = f2bf(acc[i][jv*4+3] + bias[n0 + tx*8 + jv*4 + 3]);
      *(ushort4*)(C + rb + jv*4) = v;
    }
  }
}

// ---------------- bf16 MFMA GEMM, software-pipelined staging (round 13) ----------------
__global__ __launch_bounds__(256)
void gemm_m_k(const float* __restrict__ A, const unsigned short* __restrict__ Wt,
              const float* __restrict__ bias, unsigned short* __restrict__ C) {
  __shared__ unsigned short Al[128 * 40];
  __shared__ unsigned short Bl[128 * 40];
  const int tid = threadIdx.x;
  const int m0 = blockIdx.y * 128, n0 = blockIdx.x * 128;
  const int wave = tid >> 6, lane = tid & 63;
  const int wm = wave >> 1, wn = wave & 1;
  const int l15 = lane & 15, lh = lane >> 4;
  floatx4 acc[4][4];
#pragma unroll
  for (int i = 0; i < 4; ++i)
#pragma unroll
    for (int j = 0; j < 4; ++j) acc[i][j] = (floatx4){0.f, 0.f, 0.f, 0.f};

  const int ar = tid >> 3, ac = (tid & 7) * 4;
  const int br = tid >> 2, bc = (tid & 3) * 8;

  float4 av[4];
  uint4 bv0, bv1;
#pragma unroll
  for (int p = 0; p < 4; ++p)
    av[p] = *(const float4*)(A + (size_t)(m0 + ar + p * 32) * DD + ac);
  bv0 = *(const uint4*)(Wt + (size_t)(n0 + br) * DD + bc);
  bv1 = *(const uint4*)(Wt + (size_t)(n0 + br + 64) * DD + bc);

#pragma unroll 1
  for (int k0 = 0; k0 < DD; k0 += 32) {
    __syncthreads();
#pragma unroll
    for (int p = 0; p < 4; ++p) {
      ushort4 w4;
      w4.x = f2bf(av[p].x); w4.y = f2bf(av[p].y);
      w4.z = f2bf(av[p].z); w4.w = f2bf(av[p].w);
      *(ushort4*)&Al[(ar + p * 32) * 40 + ac] = w4;
    }
    *(uint4*)&Bl[br * 40 + bc] = bv0;
    *(uint4*)&Bl[(br + 64) * 40 + bc] = bv1;
    __syncthreads();
    if (k0 + 32 < DD) {
#pragma unroll
      for (int p = 0; p < 4; ++p)
        av[p] = *(const float4*)(A + (size_t)(m0 + ar + p * 32) * DD + k0 + 32 + ac);
      bv0 = *(const uint4*)(Wt + (size_t)(n0 + br) * DD + k0 + 32 + bc);
      bv1 = *(const uint4*)(Wt + (size_t)(n0 + br + 64) * DD + k0 + 32 + bc);
    }
    U4S8 af[4], bfr[4];
#pragma unroll
    for (int mf = 0; mf < 4; ++mf)
      af[mf].u4 = *(const uint4*)&Al[(wm * 64 + mf * 16 + l15) * 40 + lh * 8];
#pragma unroll
    for (int nf = 0; nf < 4; ++nf)
      bfr[nf].u4 = *(const uint4*)&Bl[(wn * 64 + nf * 16 + l15) * 40 + lh * 8];
#pragma unroll
    for (int mf = 0; mf < 4; ++mf)
#pragma unroll
      for (int nf = 0; nf < 4; ++nf)
        acc[mf][nf] = __builtin_amdgcn_mfma_f32_16x16x32_bf16(
            af[mf].s8, bfr[nf].s8, acc[mf][nf], 0, 0, 0);
  }
#pragma unroll
  for (int nf = 0; nf < 4; ++nf) {
    int n = n0 + wn * 64 + nf * 16 + l15;
    float bn = bias[n];
#pragma unroll
    for (int mf = 0; mf < 4; ++mf) {
      int row = m0 + wm * 64 + mf * 16 + lh * 4;
      size_t base = (size_t)row * NT + n;
#pragma unroll
      for (int e = 0; e < 4; ++e)
        C[base + (size_t)e * NT] = f2bf(acc[mf][nf][e] + bn);
    }
  }
}

// ---------------- scan: round-12 proven kernel (byte-identical) ----------------
__global__ __launch_bounds__(512, 1)
void scan_k(const unsigned short* __restrict__ gx,
            const uint4* __restrict__ Wsc,
            const float* __restrict__ xin,
            float* __restrict__ hout,
            float* __restrict__ cbuf,           // [64][512] f32
            unsigned short* __restrict__ xbu,   // [2][64][512] bf16
            unsigned int* __restrict__ flags,   // [8 bg][8 dg] monotonic
            int reverse, unsigned int step_base) {
  __shared__ float pd[8192];                    // 32 KiB partials
  const int tid = threadIdx.x;
  const int bg = blockIdx.x & 7;
  const int dg = blockIdx.x >> 3;
  const int lane = tid & 63;
  const int w = tid >> 6;
  const int batch = bg * 8 + w;
  const int dim = dg * 64 + lane;

  uint4 Wf[16];
  {
    const uint4* ws = Wsc + (size_t)dg * 8192;
#pragma unroll
    for (int f = 0; f < 16; ++f)
      Wf[f] = ws[(size_t)(w * 16 + f) * 64 + lane];
  }
  float c_reg = cbuf[batch * DD + dim];
  int t0 = reverse ? (LL - 1) : 0;
  size_t r0 = (size_t)t0 * BB + batch;
  float g_i = bf2f(gx[r0 * NT + dim]);
  float g_f = bf2f(gx[r0 * NT + 512 + dim]);
  float g_c = bf2f(gx[r0 * NT + 1024 + dim]);
  float x_v = xin[r0 * DD + dim];
  const int arow = lane & 7, lh = lane >> 4;

#pragma unroll 1
  for (int s = 0; s < LL; ++s) {
    unsigned int need = step_base + (unsigned int)s;
    // ---- per-wave gate: partner block (bg, w) has published step s-1 ----
    {
      const unsigned int* f = flags + bg * 8 + w;
      while (__hip_atomic_load(f, __ATOMIC_RELAXED, __HIP_MEMORY_SCOPE_AGENT) < need)
        __builtin_amdgcn_s_sleep(1);
    }
    // ---- A-frags direct from exchange buffer, parity (s+1)&1 ----
    const ull* src = (const ull*)xbu + (size_t)(((s + 1) & 1)) * 8192;
    int ai = (bg * 8 + arow) * 128 + w * 16 + 2 * lh;
    ull v0 = __hip_atomic_load(&src[ai],     __ATOMIC_RELAXED, __HIP_MEMORY_SCOPE_AGENT);
    ull v1 = __hip_atomic_load(&src[ai + 1], __ATOMIC_RELAXED, __HIP_MEMORY_SCOPE_AGENT);
    ull v2 = __hip_atomic_load(&src[ai + 8], __ATOMIC_RELAXED, __HIP_MEMORY_SCOPE_AGENT);
    ull v3 = __hip_atomic_load(&src[ai + 9], __ATOMIC_RELAXED, __HIP_MEMORY_SCOPE_AGENT);
    // ---- MFMA partials over this wave's K-slice ----
    U4S8 A0, A1;
    A0.u4 = make_uint4((unsigned int)v0, (unsigned int)(v0 >> 32),
                       (unsigned int)v1, (unsigned int)(v1 >> 32));
    A1.u4 = make_uint4((unsigned int)v2, (unsigned int)(v2 >> 32),
                       (unsigned int)v3, (unsigned int)(v3 >> 32));
#pragma unroll
    for (int ct = 0; ct < 8; ++ct) {
      U4S8 B0, B1; B0.u4 = Wf[ct * 2]; B1.u4 = Wf[ct * 2 + 1];
      floatx4 acc = __builtin_amdgcn_mfma_f32_16x16x32_bf16(
          A0.s8, B0.s8, (floatx4){0.f, 0.f, 0.f, 0.f}, 0, 0, 0);
      acc = __builtin_amdgcn_mfma_f32_16x16x32_bf16(A1.s8, B1.s8, acc, 0, 0, 0);
      if (lane < 32) {
        int colb = ct * 16 + (lane & 15);
        int rb = (lane >> 4) * 4;
#pragma unroll
        for (int e = 0; e < 4; ++e)
          pd[(w * 8 + rb + e) * 128 + colb] = acc[e];
      }
    }
    __syncthreads();
    // ---- reduce + gates (wave w owns batch bg*8+w, dim = dg*64+lane) ----
    float gsi = 0.f, gsf = 0.f;
#pragma unroll
    for (int ww = 0; ww < 8; ++ww) {
      gsi += pd[(ww * 8 + w) * 128 + lane];
      gsf += pd[(ww * 8 + w) * 128 + 64 + lane];
    }
    float iv = 1.f / (1.f + __expf(-(g_i + gsi)));
    float fv = 1.f / (1.f + __expf(-(g_f + gsf)));
    float cn = fmaf(fv, c_reg, iv * g_c);
    // ---- publish ONLY (2B relaxed agent store; 128B contiguous per wave) ----
    __hip_atomic_store(xbu + (size_t)((s & 1)) * 32768 + batch * DD + dim,
                       f2bf(cn), __ATOMIC_RELAXED, __HIP_MEMORY_SCOPE_AGENT);
    __syncthreads();   // vmcnt(0) drain: publishes device-visible (nothing else pending)
    if (tid == 0)
      __hip_atomic_store(&flags[bg * 8 + dg], need + 1u,
                         __ATOMIC_RELAXED, __HIP_MEMORY_SCOPE_AGENT);
    // ---- off-critical tail AFTER the flag: hout + next-step prefetch ----
    int t = reverse ? (LL - 1 - s) : s;
    size_t rowg = (size_t)t * BB + batch;
    hout[rowg * DD + dim] = tanhf(cn) + x_v;
    c_reg = cn;
    int sn = (s + 1 < LL) ? s + 1 : s;
    int tn = reverse ? (LL - 1 - sn) : sn;
    size_t rn = (size_t)tn * BB + batch;
    g_i = bf2f(gx[rn * NT + dim]);
    g_f = bf2f(gx[rn * NT + 512 + dim]);
    g_c = bf2f(gx[rn * NT + 1024 + dim]);
    x_v = xin[rn * DD + dim];
  }
  cbuf[batch * DD + dim] = c_reg;
}

extern "C" void kernel_launch(void* const* d_in, const int* in_sizes, int n_in,
                              void* d_out, int out_size, void* d_ws, size_t ws_size,
                              hipStream_t stream) {
  const int* xs = (const int*)d_in[0];
  const float* emb = (const float*)d_in[1];
  const float* Wx = (const float*)d_in[2];
  const float* Wc = (const float*)d_in[3];
  const float* bias = (const float*)d_in[4];
  float* out = (float*)d_out;
  char* ws = (char*)d_ws;

  unsigned short* gx = (unsigned short*)ws;                          // 96 MiB
  float* xB = (float*)(ws + (size_t)100663296);                      // 64 MiB
  unsigned int* Wp = (unsigned int*)(ws + (size_t)167772160);        // 4 MiB
  float* cbuf = (float*)(ws + (size_t)171966464);                    // 128 KiB
  unsigned short* xbu = (unsigned short*)(ws + (size_t)172097536);   // 128 KiB
  unsigned int* flags = (unsigned int*)(ws + (size_t)172228608);     // 256 B
  unsigned short* Wxp = (unsigned short*)(ws + (size_t)172229632);   // 6 MiB
  const size_t NEED = 178521088ull;
  const bool use_mfma_gemm = (ws_size >= NEED);

  hipMemsetAsync(cbuf, 0, 131072, stream);
  hipMemsetAsync(xbu, 0, 131072, stream);    // seed parity-1 with bf16(c0)=0
  hipMemsetAsync(flags, 0, 256, stream);
  pack_wc_k<<<4096, 256, 0, stream>>>(Wc, Wp);
  if (use_mfma_gemm)
    pack_wx_k<<<dim3(8, 24, 4), 256, 0, stream>>>(Wx, Wxp);
  gather_k<<<MROWS * 128 / 256, 256, 0, stream>>>(xs, emb, out);

  for (int s = 0; s < 4; ++s) {
    const float* xin = (s % 2 == 0) ? out : xB;
    float* xout = (s % 2 == 0) ? xB : out;
    if (use_mfma_gemm)
      gemm_m_k<<<dim3(NT / 128, MROWS / 128), 256, 0, stream>>>(
          xin, Wxp + (size_t)s * NT * DD, bias + (size_t)s * NT, gx);
    else
      gemm_k<<<dim3(NT / 128, MROWS / 128), 256, 0, stream>>>(
          xin, Wx + (size_t)s * DD * NT, bias + (size_t)s * NT, gx);
    scan_k<<<64, 512, 0, stream>>>(
        gx, (const uint4*)(Wp + (size_t)s * 262144), xin, xout, cbuf, xbu, flags,
        s & 1, (unsigned int)(s * 512));
  }
}